// Round 1
// baseline (1798.744 us; speedup 1.0000x reference)
//
#include <hip/hip_runtime.h>
#include <stdint.h>

#define QN   256
#define DN   768
#define NNV  400000
#define NCK  24          // 768 / 32
#define NTILES 6250      // 400000 / 64
#define MAXBLK 768

typedef __bf16 bf16x8 __attribute__((ext_vector_type(8)));
typedef float  f32x4  __attribute__((ext_vector_type(4)));
typedef int    i32x4  __attribute__((ext_vector_type(4)));

static __device__ __forceinline__ uint16_t f2bf(float f) {
  uint32_t u = __float_as_uint(f);
  u += 0x7fffu + ((u >> 16) & 1u);   // RNE
  return (uint16_t)(u >> 16);
}

// ---------------- phase 0: normalize query, pack bf16 A as [24][256][32] ----
__global__ __launch_bounds__(256) void prep_kernel(
    const float* __restrict__ query, uint16_t* __restrict__ Abf)
{
  __shared__ float red[256];
  const int r = blockIdx.x, t = threadIdx.x;
  float a0 = query[r * DN + t];
  float a1 = query[r * DN + t + 256];
  float a2 = query[r * DN + t + 512];
  red[t] = fabsf(a0) + fabsf(a1) + fabsf(a2);
  __syncthreads();
  for (int st = 128; st > 0; st >>= 1) {
    if (t < st) red[t] += red[t + st];
    __syncthreads();
  }
  float inv = 1.0f / fmaxf(red[0], 1e-12f);
  int   ks[3] = {t, t + 256, t + 512};
  float vs[3] = {a0, a1, a2};
#pragma unroll
  for (int i = 0; i < 3; ++i) {
    int k = ks[i];
    Abf[(((k >> 5) * QN) + r) * 32 + (k & 31)] = f2bf(vs[i] * inv);
  }
}

// ---------------- phase 1: bf16 MFMA GEMM + fused per-query top-8 filter ----
__global__ __launch_bounds__(256, 2) void simtop_kernel(
    const float* __restrict__ emb, const uint16_t* __restrict__ Abf,
    const int* __restrict__ startp, const int* __restrict__ endp,
    uint2* __restrict__ cand, int nblk)
{
  __shared__ __align__(16) uint16_t Alds[QN * 32];   // 16384 B
  __shared__ __align__(16) uint16_t Blds[64 * 32];   //  4096 B
  __shared__ __align__(16) float    sT[32 * 260];    // 33280 B (stride 260: conflict-free)

  const int t    = threadIdx.x;
  const int wave = t >> 6;
  const int lane = t & 63;
  const int l15  = lane & 15;
  const int quad = lane >> 4;
  const int start = *startp;
  const int end   = *endp;

  float tv[8]; int ti[8];
#pragma unroll
  for (int j = 0; j < 8; ++j) { tv[j] = -__builtin_inff(); ti[j] = 0x7fffffff; }

  for (int tile = blockIdx.x; tile < NTILES; tile += nblk) {
    const int n0 = tile * 64;
    f32x4 acc[4][4];
#pragma unroll
    for (int a = 0; a < 4; ++a)
#pragma unroll
      for (int b = 0; b < 4; ++b)
        acc[a][b] = (f32x4){0.f, 0.f, 0.f, 0.f};

    // preload B regs for ck = 0 : lane -> col n0+lane, wave -> k rows [8w,8w+8)
    float br[8];
    {
      const float* p = emb + (size_t)(wave * 8) * NNV + n0 + lane;
#pragma unroll
      for (int j = 0; j < 8; ++j) br[j] = p[(size_t)j * NNV];
    }

    for (int ck = 0; ck < NCK; ++ck) {
      __syncthreads();                      // prev MFMA reads done; LDS writable
      // A stage: async global->LDS, 4 x (64 lanes x 16B) per wave
      {
        const char* ag = (const char*)Abf + (size_t)ck * QN * 32 * 2;
#pragma unroll
        for (int i = 0; i < 4; ++i) {
          int off = wave * 4096 + i * 1024;
          __builtin_amdgcn_global_load_lds(
              (__attribute__((address_space(1))) void*)(uintptr_t)(ag + off + lane * 16),
              (__attribute__((address_space(3))) void*)(uintptr_t)((char*)Alds + off),
              16, 0, 0);
        }
      }
      // B stage: fp32 regs -> bf16 -> LDS [n][k] (16B per lane)
      {
        uint32_t pk[4];
#pragma unroll
        for (int i = 0; i < 4; ++i)
          pk[i] = (uint32_t)f2bf(br[2 * i]) | ((uint32_t)f2bf(br[2 * i + 1]) << 16);
        i32x4 w; w.x = (int)pk[0]; w.y = (int)pk[1]; w.z = (int)pk[2]; w.w = (int)pk[3];
        *(i32x4*)((char*)Blds + lane * 64 + wave * 16) = w;
      }
      __syncthreads();                      // staging visible (drains gll)
      // prefetch next B chunk (overlaps MFMA phase)
      if (ck + 1 < NCK) {
        const float* p = emb + ((size_t)(ck + 1) * 32 + wave * 8) * NNV + n0 + lane;
#pragma unroll
        for (int j = 0; j < 8; ++j) br[j] = p[(size_t)j * NNV];
      }
      // MFMA: wave computes rows [64w,64w+64) x cols [n0, n0+64)
      bf16x8 af[4];
#pragma unroll
      for (int rf = 0; rf < 4; ++rf)
        af[rf] = *(const bf16x8*)((const char*)Alds +
                   (wave * 64 + rf * 16 + l15) * 64 + quad * 16);
#pragma unroll
      for (int cf = 0; cf < 4; ++cf) {
        bf16x8 bfv = *(const bf16x8*)((const char*)Blds +
                      (cf * 16 + l15) * 64 + quad * 16);
#pragma unroll
        for (int rf = 0; rf < 4; ++rf)
          acc[rf][cf] = __builtin_amdgcn_mfma_f32_16x16x32_bf16(af[rf], bfv, acc[rf][cf], 0, 0, 0);
      }
    }

    // selection: two 32-col halves through sT (transposed: [col][row])
#pragma unroll
    for (int h = 0; h < 2; ++h) {
      __syncthreads();
#pragma unroll
      for (int cf2 = 0; cf2 < 2; ++cf2) {
        const int cf = 2 * h + cf2;
        const int c  = cf2 * 16 + l15;      // D col = lane&15
#pragma unroll
        for (int rf = 0; rf < 4; ++rf) {
          const int row = wave * 64 + rf * 16 + quad * 4;  // D row = quad*4+reg
          *(f32x4*)(&sT[c * 260 + row]) = acc[rf][cf];
        }
      }
      __syncthreads();
      const int nb = n0 + h * 32;
#pragma unroll 4
      for (int c = 0; c < 32; ++c) {
        float v = sT[c * 260 + t];          // thread t owns query t; conflict-free
        int   n = nb + c;
        bool ok = (n < start) || (n >= end);
        if (ok && v > tv[7]) {
          tv[7] = v; ti[7] = n;
#pragma unroll
          for (int j = 7; j >= 1; --j) {
            if (tv[j] > tv[j - 1]) {
              float tf = tv[j - 1]; tv[j - 1] = tv[j]; tv[j] = tf;
              int   tn = ti[j - 1]; ti[j - 1] = ti[j]; ti[j] = tn;
            }
          }
        }
      }
    }
  }

  uint2* dst = cand + ((size_t)blockIdx.x * QN + t) * 8;
#pragma unroll
  for (int j = 0; j < 8; ++j)
    dst[j] = make_uint2(__float_as_uint(tv[j]), (unsigned)ti[j]);
}

// ---------------- phase 2: merge block lists, exact fp32 rescore, top-4 -----
__global__ __launch_bounds__(256) void final_kernel(
    const float* __restrict__ query, const float* __restrict__ emb,
    const uint2* __restrict__ cand, int nblk, float* __restrict__ out)
{
  __shared__ float sv[256];
  __shared__ int   si[256];
  __shared__ float gv[8];
  __shared__ int   gi[8];
  __shared__ float red8[256 * 8];

  const int q = blockIdx.x, t = threadIdx.x;

  float tv[8]; int ti[8];
#pragma unroll
  for (int j = 0; j < 8; ++j) { tv[j] = -__builtin_inff(); ti[j] = 0x7fffffff; }

  for (int b = t; b < nblk; b += 256) {
    const uint2* p = cand + ((size_t)b * QN + q) * 8;
#pragma unroll
    for (int j = 0; j < 8; ++j) {
      uint2 e = p[j];
      float v = __uint_as_float(e.x);
      int   n = (int)e.y;
      if (v > tv[7] || (v == tv[7] && n < ti[7])) {
        tv[7] = v; ti[7] = n;
#pragma unroll
        for (int k = 7; k >= 1; --k) {
          if (tv[k] > tv[k - 1] || (tv[k] == tv[k - 1] && ti[k] < ti[k - 1])) {
            float tf = tv[k - 1]; tv[k - 1] = tv[k]; tv[k] = tf;
            int   tn = ti[k - 1]; ti[k - 1] = ti[k]; ti[k] = tn;
          }
        }
      }
    }
  }

  // global top-8 = 8 x block-wide argmax; winner shifts its list down
  for (int k = 0; k < 8; ++k) {
    sv[t] = tv[0]; si[t] = ti[0];
    __syncthreads();
    for (int st = 128; st > 0; st >>= 1) {
      if (t < st) {
        float ov = sv[t + st]; int oi = si[t + st];
        if (ov > sv[t] || (ov == sv[t] && oi < si[t])) { sv[t] = ov; si[t] = oi; }
      }
      __syncthreads();
    }
    if (t == 0) { gv[k] = sv[0]; gi[k] = si[0]; }
    __syncthreads();
    if (tv[0] == gv[k] && ti[0] == gi[k]) {
#pragma unroll
      for (int j = 0; j < 7; ++j) { tv[j] = tv[j + 1]; ti[j] = ti[j + 1]; }
      tv[7] = -__builtin_inff(); ti[7] = 0x7fffffff;
    }
  }

  // exact L1 norm of this query row
  float a0 = query[q * DN + t], a1 = query[q * DN + t + 256], a2 = query[q * DN + t + 512];
  sv[t] = fabsf(a0) + fabsf(a1) + fabsf(a2);
  __syncthreads();
  for (int st = 128; st > 0; st >>= 1) {
    if (t < st) sv[t] += sv[t + st];
    __syncthreads();
  }
  float norm = fmaxf(sv[0], 1e-12f);

  // exact fp32 rescore of the 8 candidates
#pragma unroll
  for (int c = 0; c < 8; ++c) {
    int n = gi[c];
    bool ok = (n >= 0) && (n < NNV);
    int nn = ok ? n : 0;
    float d0 = emb[(size_t)t * NNV + nn];
    float d1 = emb[(size_t)(t + 256) * NNV + nn];
    float d2 = emb[(size_t)(t + 512) * NNV + nn];
    red8[t * 8 + c] = a0 * d0 + a1 * d1 + a2 * d2;
  }
  __syncthreads();
  for (int st = 128; st > 0; st >>= 1) {
    if (t < st) {
#pragma unroll
      for (int c = 0; c < 8; ++c) red8[t * 8 + c] += red8[(t + st) * 8 + c];
    }
    __syncthreads();
  }

  if (t == 0) {
    float fv[8]; int fi[8];
#pragma unroll
    for (int c = 0; c < 8; ++c) {
      int n = gi[c];
      bool ok = (n >= 0) && (n < NNV);
      fv[c] = ok ? (red8[c] / norm) : -__builtin_inff();
      fi[c] = n;
    }
    for (int a = 0; a < 4; ++a) {
      int best = a;
      for (int b2 = a + 1; b2 < 8; ++b2)
        if (fv[b2] > fv[best] || (fv[b2] == fv[best] && fi[b2] < fi[best])) best = b2;
      float tf = fv[a]; fv[a] = fv[best]; fv[best] = tf;
      int   tn = fi[a]; fi[a] = fi[best]; fi[best] = tn;
      out[q * 4 + a]        = fv[a];
      out[1024 + q * 4 + a] = (float)fi[a];   // indices exact in fp32 (< 2^24)
    }
  }
}

extern "C" void kernel_launch(void* const* d_in, const int* in_sizes, int n_in,
                              void* d_out, int out_size, void* d_ws, size_t ws_size,
                              hipStream_t stream) {
  const float* query = (const float*)d_in[0];
  const float* emb   = (const float*)d_in[1];
  const int* startp  = (const int*)d_in[2];
  const int* endp    = (const int*)d_in[3];
  float* out = (float*)d_out;

  uint16_t* Abf = (uint16_t*)d_ws;
  const size_t A_BYTES = (size_t)NCK * QN * 32 * 2;          // 393216
  uint2* cand = (uint2*)((char*)d_ws + A_BYTES);

  int nblk = MAXBLK;
  const size_t per_blk = (size_t)QN * 8 * 8;                 // 16384 B per block
  if (ws_size < A_BYTES + (size_t)nblk * per_blk) {
    size_t avail = (ws_size > A_BYTES) ? (ws_size - A_BYTES) : per_blk;
    nblk = (int)(avail / per_blk);
    if (nblk < 1) nblk = 1;
    if (nblk > MAXBLK) nblk = MAXBLK;
  }

  hipLaunchKernelGGL(prep_kernel, dim3(QN), dim3(256), 0, stream, query, Abf);
  hipLaunchKernelGGL(simtop_kernel, dim3(nblk), dim3(256), 0, stream,
                     emb, Abf, startp, endp, cand, nblk);
  hipLaunchKernelGGL(final_kernel, dim3(QN), dim3(256), 0, stream,
                     query, emb, cand, nblk, out);
}

// Round 2
// 1732.724 us; speedup vs baseline: 1.0381x; 1.0381x over previous
//
#include <hip/hip_runtime.h>
#include <stdint.h>

#define QN   256
#define DN   768
#define NNV  400000
#define NCK  24          // 768 / 32
#define NTILES 6250      // 400000 / 64
#define NBLK 1024        // 4 blocks/CU x 256 CUs

typedef __bf16 bf16x8 __attribute__((ext_vector_type(8)));
typedef float  f32x4  __attribute__((ext_vector_type(4)));
typedef int    i32x4  __attribute__((ext_vector_type(4)));

static __device__ __forceinline__ uint16_t f2bf(float f) {
  uint32_t u = __float_as_uint(f);
  u += 0x7fffu + ((u >> 16) & 1u);   // RNE
  return (uint16_t)(u >> 16);
}

// ---------------- phase 0: normalize query, pack bf16 A as [24][256][32] ----
__global__ __launch_bounds__(256) void prep_kernel(
    const float* __restrict__ query, uint16_t* __restrict__ Abf)
{
  __shared__ float red[256];
  const int r = blockIdx.x, t = threadIdx.x;
  float a0 = query[r * DN + t];
  float a1 = query[r * DN + t + 256];
  float a2 = query[r * DN + t + 512];
  red[t] = fabsf(a0) + fabsf(a1) + fabsf(a2);
  __syncthreads();
  for (int st = 128; st > 0; st >>= 1) {
    if (t < st) red[t] += red[t + st];
    __syncthreads();
  }
  float inv = 1.0f / fmaxf(red[0], 1e-12f);
  int   ks[3] = {t, t + 256, t + 512};
  float vs[3] = {a0, a1, a2};
#pragma unroll
  for (int i = 0; i < 3; ++i) {
    int k = ks[i];
    Abf[(((k >> 5) * QN) + r) * 32 + (k & 31)] = f2bf(vs[i] * inv);
  }
}

// ---------------- phase 1: bf16 MFMA GEMM + fused per-query top-8 filter ----
// LDS union: gemm phase uses double-buffered A (2x16384 B) + B (2x4096 B) =
// 40960 B; selection phase reuses the same memory as sT (32x260 f32 =
// 33280 B). 40960 B -> exactly 4 blocks/CU (163840 B LDS).
__global__ __launch_bounds__(256, 4) void simtop_kernel(
    const float* __restrict__ emb, const uint16_t* __restrict__ Abf,
    const int* __restrict__ startp, const int* __restrict__ endp,
    uint2* __restrict__ cand)
{
  __shared__ __align__(16) char smem[40960];
  uint16_t* Alds = (uint16_t*)smem;             // [2][QN*32] bf16
  uint16_t* Blds = (uint16_t*)(smem + 32768);   // [2][64*32] bf16
  float*    sT   = (float*)smem;                // [32][260] f32 (aliased)

  const int t    = threadIdx.x;
  const int wave = t >> 6;
  const int lane = t & 63;
  const int l15  = lane & 15;
  const int quad = lane >> 4;
  const int start = *startp;
  const int end   = *endp;

  float tv[8]; int ti[8];
#pragma unroll
  for (int j = 0; j < 8; ++j) { tv[j] = -__builtin_inff(); ti[j] = 0x7fffffff; }

  // per-thread invariant offsets
  const char* agBase = (const char*)Abf + wave * 4096 + lane * 16;
  char*       alBase = (char*)0 + wave * 4096;                // offset only
  const float* ebBase = emb + (size_t)(wave * 8) * NNV + lane; // + ck*32*NNV + n0

  int tile = blockIdx.x;
  float br[8];
  // preload B regs for (tile, ck=0)
  {
    const float* p = ebBase + tile * 64;
#pragma unroll
    for (int j = 0; j < 8; ++j) br[j] = p[(size_t)j * NNV];
  }

  for (; tile < NTILES; tile += NBLK) {
    const int n0 = tile * 64;
    const int tnext = (tile + NBLK < NTILES) ? (tile + NBLK) : tile;

    f32x4 acc[4][4];
#pragma unroll
    for (int a = 0; a < 4; ++a)
#pragma unroll
      for (int b = 0; b < 4; ++b)
        acc[a][b] = (f32x4){0.f, 0.f, 0.f, 0.f};

    __syncthreads();   // previous tile's sT scan done; LDS free for staging

    // ---- prologue: stage ck=0 into buffer 0 ----
    {
#pragma unroll
      for (int i = 0; i < 4; ++i)
        __builtin_amdgcn_global_load_lds(
            (__attribute__((address_space(1))) void*)(uintptr_t)(agBase + i * 1024),
            (__attribute__((address_space(3))) void*)(uintptr_t)(smem + (uintptr_t)alBase + i * 1024),
            16, 0, 0);
      uint32_t pk[4];
#pragma unroll
      for (int i = 0; i < 4; ++i)
        pk[i] = (uint32_t)f2bf(br[2 * i]) | ((uint32_t)f2bf(br[2 * i + 1]) << 16);
      i32x4 w; w.x = (int)pk[0]; w.y = (int)pk[1]; w.z = (int)pk[2]; w.w = (int)pk[3];
      *(i32x4*)((char*)Blds + lane * 64 + wave * 16) = w;
      // prefetch br <- (tile, ck=1)
      const float* p = ebBase + (size_t)32 * NNV + n0;
#pragma unroll
      for (int j = 0; j < 8; ++j) br[j] = p[(size_t)j * NNV];
    }
    __syncthreads();

    // ---- main K loop: single barrier per ck ----
    for (int ck = 0; ck < NCK; ++ck) {
      const int cur = ck & 1, nxt = cur ^ 1;
      if (ck < NCK - 1) {
        // stage A chunk ck+1 -> A[nxt] (async, drains at end-of-iter barrier)
        const char* ag = agBase + (size_t)(ck + 1) * 16384;
        char* al = smem + nxt * 16384 + (uintptr_t)alBase;
#pragma unroll
        for (int i = 0; i < 4; ++i)
          __builtin_amdgcn_global_load_lds(
              (__attribute__((address_space(1))) void*)(uintptr_t)(ag + i * 1024),
              (__attribute__((address_space(3))) void*)(uintptr_t)(al + i * 1024),
              16, 0, 0);
        // pack br (holds ck+1 data) -> B[nxt]
        uint32_t pk[4];
#pragma unroll
        for (int i = 0; i < 4; ++i)
          pk[i] = (uint32_t)f2bf(br[2 * i]) | ((uint32_t)f2bf(br[2 * i + 1]) << 16);
        i32x4 w; w.x = (int)pk[0]; w.y = (int)pk[1]; w.z = (int)pk[2]; w.w = (int)pk[3];
        *(i32x4*)((char*)Blds + nxt * 4096 + lane * 64 + wave * 16) = w;
        // register-prefetch br for ck+2 (or next tile's ck0 at ck==22)
        if (ck < NCK - 2) {
          const float* p = ebBase + (size_t)(ck + 2) * 32 * NNV + n0;
#pragma unroll
          for (int j = 0; j < 8; ++j) br[j] = p[(size_t)j * NNV];
        } else {
          const float* p = ebBase + tnext * 64;
#pragma unroll
          for (int j = 0; j < 8; ++j) br[j] = p[(size_t)j * NNV];
        }
      }
      // MFMA on current buffers
      const char* Ab = (const char*)Alds + cur * 16384;
      const char* Bb = (const char*)Blds + cur * 4096;
      bf16x8 af[4];
#pragma unroll
      for (int rf = 0; rf < 4; ++rf)
        af[rf] = *(const bf16x8*)(Ab + (wave * 64 + rf * 16 + l15) * 64 + quad * 16);
#pragma unroll
      for (int cf = 0; cf < 4; ++cf) {
        bf16x8 bfv = *(const bf16x8*)(Bb + (cf * 16 + l15) * 64 + quad * 16);
#pragma unroll
        for (int rf = 0; rf < 4; ++rf)
          acc[rf][cf] = __builtin_amdgcn_mfma_f32_16x16x32_bf16(af[rf], bfv, acc[rf][cf], 0, 0, 0);
      }
      __syncthreads();  // drain gll + protect cur from next-iter overwrite
    }

    // ---- selection: two 32-col halves through sT (transposed [col][row]) ----
#pragma unroll
    for (int h = 0; h < 2; ++h) {
      if (h) __syncthreads();   // h0 scan done before overwriting sT
#pragma unroll
      for (int cf2 = 0; cf2 < 2; ++cf2) {
        const int cf = 2 * h + cf2;
        const int c  = cf2 * 16 + l15;      // D col = lane&15
#pragma unroll
        for (int rf = 0; rf < 4; ++rf) {
          const int row = wave * 64 + rf * 16 + quad * 4;  // D row = quad*4+reg
          *(f32x4*)(&sT[c * 260 + row]) = acc[rf][cf];
        }
      }
      __syncthreads();
      const int nb = n0 + h * 32;
#pragma unroll 4
      for (int c = 0; c < 32; ++c) {
        float v = sT[c * 260 + t];          // thread t owns query t; stride-1
        int   n = nb + c;
        bool ok = (n < start) || (n >= end);
        if (ok && v > tv[7]) {
          tv[7] = v; ti[7] = n;
#pragma unroll
          for (int j = 7; j >= 1; --j) {
            if (tv[j] > tv[j - 1]) {
              float tf = tv[j - 1]; tv[j - 1] = tv[j]; tv[j] = tf;
              int   tn = ti[j - 1]; ti[j - 1] = ti[j]; ti[j] = tn;
            }
          }
        }
      }
    }
  }

  uint2* dst = cand + ((size_t)blockIdx.x * QN + t) * 8;
#pragma unroll
  for (int j = 0; j < 8; ++j)
    dst[j] = make_uint2(__float_as_uint(tv[j]), (unsigned)ti[j]);
}

// ---------------- phase 2: merge block lists, exact fp32 rescore, top-4 -----
__global__ __launch_bounds__(256) void final_kernel(
    const float* __restrict__ query, const float* __restrict__ emb,
    const uint2* __restrict__ cand, int nblk, float* __restrict__ out)
{
  __shared__ float sv[256];
  __shared__ int   si[256];
  __shared__ float gv[8];
  __shared__ int   gi[8];
  __shared__ float red8[256 * 8];

  const int q = blockIdx.x, t = threadIdx.x;

  float tv[8]; int ti[8];
#pragma unroll
  for (int j = 0; j < 8; ++j) { tv[j] = -__builtin_inff(); ti[j] = 0x7fffffff; }

  for (int b = t; b < nblk; b += 256) {
    const uint2* p = cand + ((size_t)b * QN + q) * 8;
#pragma unroll
    for (int j = 0; j < 8; ++j) {
      uint2 e = p[j];
      float v = __uint_as_float(e.x);
      int   n = (int)e.y;
      if (v > tv[7] || (v == tv[7] && n < ti[7])) {
        tv[7] = v; ti[7] = n;
#pragma unroll
        for (int k = 7; k >= 1; --k) {
          if (tv[k] > tv[k - 1] || (tv[k] == tv[k - 1] && ti[k] < ti[k - 1])) {
            float tf = tv[k - 1]; tv[k - 1] = tv[k]; tv[k] = tf;
            int   tn = ti[k - 1]; ti[k - 1] = ti[k]; ti[k] = tn;
          }
        }
      }
    }
  }

  // global top-8 = 8 x block-wide argmax; winner shifts its list down
  for (int k = 0; k < 8; ++k) {
    sv[t] = tv[0]; si[t] = ti[0];
    __syncthreads();
    for (int st = 128; st > 0; st >>= 1) {
      if (t < st) {
        float ov = sv[t + st]; int oi = si[t + st];
        if (ov > sv[t] || (ov == sv[t] && oi < si[t])) { sv[t] = ov; si[t] = oi; }
      }
      __syncthreads();
    }
    if (t == 0) { gv[k] = sv[0]; gi[k] = si[0]; }
    __syncthreads();
    if (tv[0] == gv[k] && ti[0] == gi[k]) {
#pragma unroll
      for (int j = 0; j < 7; ++j) { tv[j] = tv[j + 1]; ti[j] = ti[j + 1]; }
      tv[7] = -__builtin_inff(); ti[7] = 0x7fffffff;
    }
  }

  // exact L1 norm of this query row
  float a0 = query[q * DN + t], a1 = query[q * DN + t + 256], a2 = query[q * DN + t + 512];
  sv[t] = fabsf(a0) + fabsf(a1) + fabsf(a2);
  __syncthreads();
  for (int st = 128; st > 0; st >>= 1) {
    if (t < st) sv[t] += sv[t + st];
    __syncthreads();
  }
  float norm = fmaxf(sv[0], 1e-12f);

  // exact fp32 rescore of the 8 candidates
#pragma unroll
  for (int c = 0; c < 8; ++c) {
    int n = gi[c];
    bool ok = (n >= 0) && (n < NNV);
    int nn = ok ? n : 0;
    float d0 = emb[(size_t)t * NNV + nn];
    float d1 = emb[(size_t)(t + 256) * NNV + nn];
    float d2 = emb[(size_t)(t + 512) * NNV + nn];
    red8[t * 8 + c] = a0 * d0 + a1 * d1 + a2 * d2;
  }
  __syncthreads();
  for (int st = 128; st > 0; st >>= 1) {
    if (t < st) {
#pragma unroll
      for (int c = 0; c < 8; ++c) red8[t * 8 + c] += red8[(t + st) * 8 + c];
    }
    __syncthreads();
  }

  if (t == 0) {
    float fv[8]; int fi[8];
#pragma unroll
    for (int c = 0; c < 8; ++c) {
      int n = gi[c];
      bool ok = (n >= 0) && (n < NNV);
      fv[c] = ok ? (red8[c] / norm) : -__builtin_inff();
      fi[c] = n;
    }
    for (int a = 0; a < 4; ++a) {
      int best = a;
      for (int b2 = a + 1; b2 < 8; ++b2)
        if (fv[b2] > fv[best] || (fv[b2] == fv[best] && fi[b2] < fi[best])) best = b2;
      float tf = fv[a]; fv[a] = fv[best]; fv[best] = tf;
      int   tn = fi[a]; fi[a] = fi[best]; fi[best] = tn;
      out[q * 4 + a]        = fv[a];
      out[1024 + q * 4 + a] = (float)fi[a];   // indices exact in fp32 (< 2^24)
    }
  }
}

extern "C" void kernel_launch(void* const* d_in, const int* in_sizes, int n_in,
                              void* d_out, int out_size, void* d_ws, size_t ws_size,
                              hipStream_t stream) {
  const float* query = (const float*)d_in[0];
  const float* emb   = (const float*)d_in[1];
  const int* startp  = (const int*)d_in[2];
  const int* endp    = (const int*)d_in[3];
  float* out = (float*)d_out;

  uint16_t* Abf = (uint16_t*)d_ws;
  const size_t A_BYTES = (size_t)NCK * QN * 32 * 2;          // 393216
  uint2* cand = (uint2*)((char*)d_ws + A_BYTES);

  hipLaunchKernelGGL(prep_kernel, dim3(QN), dim3(256), 0, stream, query, Abf);
  hipLaunchKernelGGL(simtop_kernel, dim3(NBLK), dim3(256), 0, stream,
                     emb, Abf, startp, endp, cand);
  hipLaunchKernelGGL(final_kernel, dim3(QN), dim3(256), 0, stream,
                     query, emb, cand, NBLK, out);
}